// Round 1
// baseline (22.720 us; speedup 1.0000x reference)
//
#include <hip/hip_runtime.h>

#define BROWS 8192
#define EPSF 1e-7f

// ws layout (floats):
//   [0, B)            risk[i]
//   [B, 2B)           e[i] = exp(risk[i])
//   [2B, 2B+32)       nll partials   (kernel A, 32 blocks)
//   [2B+32, +512)     rank partials  (kernel B, 512 blocks)
//   [.. , +512)       count partials (kernel B, 512 blocks)

__device__ __forceinline__ float wave_reduce_sum(float v) {
    #pragma unroll
    for (int off = 32; off > 0; off >>= 1) v += __shfl_xor(v, off, 64);
    return v;
}

// ---------- Kernel A: per-row NLL + risk + exp(risk) ----------
__global__ __launch_bounds__(256) void row_kernel(
        const float4* __restrict__ outputs, const int* __restrict__ y,
        const int* __restrict__ c, float* __restrict__ risk,
        float* __restrict__ e, float* __restrict__ nll_part) {
    __shared__ float s_wave[4];
    int i = blockIdx.x * 256 + threadIdx.x;
    float4 o = outputs[i];

    float h0 = 1.f / (1.f + expf(-o.x));
    float h1 = 1.f / (1.f + expf(-o.y));
    float h2 = 1.f / (1.f + expf(-o.z));
    float h3 = 1.f / (1.f + expf(-o.w));

    float Sp0 = 1.f;
    float Sp1 = Sp0 * (1.f - h0);
    float Sp2 = Sp1 * (1.f - h1);
    float Sp3 = Sp2 * (1.f - h2);
    float Sp4 = Sp3 * (1.f - h3);

    int yi = y[i];
    // static-select (avoid runtime-indexed local arrays -> scratch)
    float s_prev = (yi == 0) ? Sp0 : (yi == 1) ? Sp1 : (yi == 2) ? Sp2 : Sp3;
    float s_this = (yi == 0) ? Sp1 : (yi == 1) ? Sp2 : (yi == 2) ? Sp3 : Sp4;
    float h_this = (yi == 0) ? h0  : (yi == 1) ? h1  : (yi == 2) ? h2  : h3;

    s_prev = fmaxf(s_prev, EPSF);
    s_this = fmaxf(s_this, EPSF);
    h_this = fmaxf(h_this, EPSF);

    float cf = (float)c[i];
    float nll = -cf * logf(s_this) - (1.f - cf) * (logf(s_prev) + logf(h_this));

    float r = -(Sp1 + Sp2 + Sp3 + Sp4);   // risk in (-4, 0)
    risk[i] = r;
    e[i] = expf(r);                        // in [e^-4, 1] -> safe unshifted sums

    // block-reduce nll -> one partial per block (deterministic)
    float ws = wave_reduce_sum(nll);
    int lane = threadIdx.x & 63, wave = threadIdx.x >> 6;
    if (lane == 0) s_wave[wave] = ws;
    __syncthreads();
    if (threadIdx.x == 0) {
        float s = s_wave[0] + s_wave[1] + s_wave[2] + s_wave[3];
        nll_part[blockIdx.x] = s;
    }
}

// ---------- Kernel B: pairwise masked sum (one wave per row) ----------
// lse_i = log( sum_{j: t_j > t_i} e_j );  valid <=> (c_i==0) && (sum > 0)
__global__ __launch_bounds__(1024) void pair_kernel(
        const float* __restrict__ t, const int* __restrict__ c,
        const float* __restrict__ risk, const float* __restrict__ e,
        float* __restrict__ rank_part, float* __restrict__ cnt_part) {
    __shared__ float2 sp[BROWS];      // 64 KB: (t_j, e_j) interleaved
    __shared__ float s_contrib[16];
    __shared__ float s_cnt[16];

    int tid = threadIdx.x;
    for (int idx = tid; idx < BROWS; idx += 1024)
        sp[idx] = make_float2(t[idx], e[idx]);
    __syncthreads();

    int wave = tid >> 6, lane = tid & 63;
    int i = blockIdx.x * 16 + wave;   // 16 rows per block, 512 blocks
    float ti = t[i];

    float acc = 0.f;
    #pragma unroll 8
    for (int k = lane; k < BROWS; k += 64) {
        float2 pe = sp[k];            // ds_read_b64, 2-way bank alias (free)
        acc += (pe.x > ti) ? pe.y : 0.f;
    }
    acc = wave_reduce_sum(acc);

    if (lane == 0) {
        bool valid = (c[i] == 0) && (acc > 0.f);
        s_contrib[wave] = valid ? (logf(acc) - risk[i]) : 0.f;
        s_cnt[wave]     = valid ? 1.f : 0.f;
    }
    __syncthreads();
    if (tid == 0) {
        float rs = 0.f, cs = 0.f;
        #pragma unroll
        for (int w = 0; w < 16; ++w) { rs += s_contrib[w]; cs += s_cnt[w]; }
        rank_part[blockIdx.x] = rs;
        cnt_part[blockIdx.x]  = cs;
    }
}

// ---------- Kernel C: final deterministic combine ----------
__global__ __launch_bounds__(512) void final_kernel(
        const float* __restrict__ nll_part, const float* __restrict__ rank_part,
        const float* __restrict__ cnt_part, float* __restrict__ out) {
    __shared__ float sh[24];
    int tid = threadIdx.x, lane = tid & 63, wave = tid >> 6;  // 8 waves
    float nll = (tid < 32) ? nll_part[tid] : 0.f;
    float rs = rank_part[tid];        // 512 partials, one per thread
    float cs = cnt_part[tid];
    nll = wave_reduce_sum(nll);
    rs  = wave_reduce_sum(rs);
    cs  = wave_reduce_sum(cs);
    if (lane == 0) { sh[wave] = nll; sh[8 + wave] = rs; sh[16 + wave] = cs; }
    __syncthreads();
    if (tid == 0) {
        float a = 0.f, b = 0.f, d = 0.f;
        #pragma unroll
        for (int w = 0; w < 8; ++w) { a += sh[w]; b += sh[8 + w]; d += sh[16 + w]; }
        float loss_nll  = a / (float)BROWS;
        float loss_rank = (d > 0.f) ? (b / fmaxf(d, 1.f)) : 0.f;
        out[0] = loss_nll + 0.5f * loss_rank;
    }
}

extern "C" void kernel_launch(void* const* d_in, const int* in_sizes, int n_in,
                              void* d_out, int out_size, void* d_ws, size_t ws_size,
                              hipStream_t stream) {
    const float4* outputs = (const float4*)d_in[0];
    const float*  t       = (const float*)d_in[1];
    const int*    y       = (const int*)d_in[2];
    const int*    c       = (const int*)d_in[3];
    float* out = (float*)d_out;

    float* ws        = (float*)d_ws;
    float* risk      = ws;
    float* e         = ws + BROWS;
    float* nll_part  = ws + 2 * BROWS;
    float* rank_part = nll_part + 32;
    float* cnt_part  = rank_part + 512;

    row_kernel<<<32, 256, 0, stream>>>(outputs, y, c, risk, e, nll_part);
    pair_kernel<<<512, 1024, 0, stream>>>(t, c, risk, e, rank_part, cnt_part);
    final_kernel<<<1, 512, 0, stream>>>(nll_part, rank_part, cnt_part, out);
}